// Round 2
// 15586.189 us; speedup vs baseline: 2.3340x; 2.3340x over previous
//
#include <hip/hip_runtime.h>
#include <math.h>

#define B_     2048
#define L_     10
#define D_     512
#define H_     8
#define V_     1974
#define DI_    2048
#define NL_    6
#define BOARD_ 70
#define ROWS_  (B_ * L_)            /* 20480 */
#define SQRT_D 22.627416997969522f

typedef __attribute__((ext_vector_type(8))) short s16x8;   // 8 bf16 (4 VGPR)
typedef __attribute__((ext_vector_type(4))) float f32x4;

// Dekker-style split: x ~= hi + lo, both bf16 (truncated). Residual ~2^-16|x|.
__device__ __forceinline__ void split2(float x, short &hi, short &lo)
{
    unsigned u = __float_as_uint(x);
    hi = (short)(u >> 16);
    float hf = __uint_as_float(u & 0xffff0000u);
    lo = (short)(__float_as_uint(x - hf) >> 16);
}

// ---------------------------------------------------------------------------
// Embedding: X[b,l,:] = emb[moves[b,l],:]*sqrt(D) + pos[l,:]
// ---------------------------------------------------------------------------
__global__ __launch_bounds__(256)
void embed_k(const int* __restrict__ moves, const float* __restrict__ emb,
             const float* __restrict__ pos, float* __restrict__ X)
{
    int idx = blockIdx.x * 256 + threadIdx.x;
    if (idx >= ROWS_ * D_) return;
    int d  = idx & 511;
    int bl = idx >> 9;
    int l  = bl % L_;
    int mv = moves[bl];
    X[idx] = emb[mv * D_ + d] * SQRT_D + pos[l * D_ + d];
}

// ---------------------------------------------------------------------------
// LayerNorm over D=512 (f32). One wave per row, 4 rows/block.
// ---------------------------------------------------------------------------
__global__ __launch_bounds__(256)
void ln_k(const float* __restrict__ X, const float* __restrict__ g,
          const float* __restrict__ bta, float* __restrict__ Y, int rows)
{
    int wave = threadIdx.x >> 6;
    int lane = threadIdx.x & 63;
    int row  = blockIdx.x * 4 + wave;
    if (row >= rows) return;
    const float* x = X + (size_t)row * D_;
    float4 t0 = *(const float4*)&x[lane * 8];
    float4 t1 = *(const float4*)&x[lane * 8 + 4];
    float v[8] = { t0.x, t0.y, t0.z, t0.w, t1.x, t1.y, t1.z, t1.w };
    float s1 = 0.f, s2 = 0.f;
    #pragma unroll
    for (int q = 0; q < 8; q++) { s1 += v[q]; s2 += v[q] * v[q]; }
    #pragma unroll
    for (int off = 32; off; off >>= 1) {
        s1 += __shfl_xor(s1, off);
        s2 += __shfl_xor(s2, off);
    }
    float m   = s1 * (1.f / D_);
    float var = s2 * (1.f / D_) - m * m;
    float r   = 1.0f / sqrtf(var + 1e-5f);
    float* y = Y + (size_t)row * D_;
    #pragma unroll
    for (int q = 0; q < 8; q++) {
        int d = lane * 8 + q;
        y[d] = (v[q] - m) * r * g[d] + bta[d];
    }
}

// ---------------------------------------------------------------------------
// Transpose + bf16 hi/lo split:  W (KxN f32, row-major) -> Thi/Tlo (NxK bf16)
// 32x32 tiles. K is always a multiple of 32; N guarded (vocab N=1974).
// ---------------------------------------------------------------------------
__global__ __launch_bounds__(256)
void tsplit_k(const float* __restrict__ W, short* __restrict__ Thi,
              short* __restrict__ Tlo, int K, int N)
{
    __shared__ float t[32][33];
    int n0 = blockIdx.x * 32, k0 = blockIdx.y * 32;
    int c = threadIdx.x & 31, r = threadIdx.x >> 5;      // r: 0..7
    #pragma unroll
    for (int i = 0; i < 4; i++) {
        int kk = k0 + r + i * 8, nn = n0 + c;
        t[r + i * 8][c] = (nn < N) ? W[(size_t)kk * N + nn] : 0.f;
    }
    __syncthreads();
    #pragma unroll
    for (int i = 0; i < 4; i++) {
        int nn = n0 + r + i * 8;     // output row (n)
        int kk = k0 + c;             // output col (k)
        if (nn < N) {
            short hi, lo; split2(t[c][r + i * 8], hi, lo);
            Thi[(size_t)nn * K + kk] = hi;
            Tlo[(size_t)nn * K + kk] = lo;
        }
    }
}

// ---------------------------------------------------------------------------
// MFMA GEMM, split-bf16 emulation of f32:
//   C(MxN) = A(MxK,f32) @ B(KxN)  where B is provided pre-transposed+split as
//   BThi/BTlo (NxK bf16).  acc += Ahi*Bhi + Ahi*Blo + Alo*Bhi  (f32 acc).
// BM=BN=128, BK=32, 256 threads = 4 waves (2x2), wave tile 64x64 (4x4 frags
// of v_mfma_f32_16x16x32_bf16). A split on the fly during staging.
// LDS fragment-major layout [kgrp][row][8] -> conflict-free b128 frag reads.
// Requires: M % 128 == 0, K % 32 == 0 (true for every call site). N guarded.
// ---------------------------------------------------------------------------
template<bool BIAS, bool RELU, bool RESID>
__global__ __launch_bounds__(256)
void mgemm_k(const float* __restrict__ A,
             const short* __restrict__ BThi, const short* __restrict__ BTlo,
             const float* __restrict__ bias, const float* __restrict__ resid,
             float* __restrict__ C, int M, int N, int K)
{
    __shared__ short Ah[4][128][8], Al[4][128][8];
    __shared__ short Bh[4][128][8], Bl[4][128][8];

    const int tid = threadIdx.x;
    const int m0 = blockIdx.y * 128, n0 = blockIdx.x * 128;

    // staging assignment
    const int ar   = tid >> 2;        // A row (pass adds +64)
    const int akg  = tid & 3;         // A k-group (8 k each)
    const int bc   = tid >> 1;        // B col 0..127
    const int bkg0 = tid & 1;         // B k-groups {bkg0, bkg0+2}

    // wave/frag geometry
    const int lane = tid & 63;
    const int wv   = tid >> 6;
    const int wm   = (wv >> 1) * 64, wn = (wv & 1) * 64;
    const int rsel = lane & 15, kg = lane >> 4;

    f32x4 acc[4][4];
    #pragma unroll
    for (int i = 0; i < 4; i++)
        #pragma unroll
        for (int j = 0; j < 4; j++)
            #pragma unroll
            for (int q = 0; q < 4; q++) acc[i][j][q] = 0.f;

    // fragment pointers (constant across the K loop; single-buffered LDS)
    const s16x8 *pAh[4], *pAl[4], *pBh[4], *pBl[4];
    #pragma unroll
    for (int x = 0; x < 4; x++) {
        pAh[x] = (const s16x8*)&Ah[kg][wm + x * 16 + rsel][0];
        pAl[x] = (const s16x8*)&Al[kg][wm + x * 16 + rsel][0];
        pBh[x] = (const s16x8*)&Bh[kg][wn + x * 16 + rsel][0];
        pBl[x] = (const s16x8*)&Bl[kg][wn + x * 16 + rsel][0];
    }

    // prefetch registers
    f32x4 pa[2][2];
    s16x8 pbh[2], pbl[2];

    auto loadA = [&](int k0) {
        #pragma unroll
        for (int p = 0; p < 2; p++) {
            const float* ap = A + (size_t)(m0 + ar + p * 64) * K + k0 + akg * 8;
            pa[p][0] = *(const f32x4*)ap;
            pa[p][1] = *(const f32x4*)(ap + 4);
        }
    };
    auto loadB = [&](int k0) {
        #pragma unroll
        for (int p = 0; p < 2; p++) {
            int col = n0 + bc, kgp = bkg0 + p * 2;
            if (col < N) {
                size_t off = (size_t)col * K + k0 + kgp * 8;
                pbh[p] = *(const s16x8*)(BThi + off);
                pbl[p] = *(const s16x8*)(BTlo + off);
            } else {
                #pragma unroll
                for (int q = 0; q < 8; q++) { pbh[p][q] = 0; pbl[p][q] = 0; }
            }
        }
    };
    auto storeLDS = [&]() {
        #pragma unroll
        for (int p = 0; p < 2; p++) {
            s16x8 h, l;
            #pragma unroll
            for (int q = 0; q < 8; q++) {
                float x = (q < 4) ? pa[p][0][q] : pa[p][1][q - 4];
                short hh, ll; split2(x, hh, ll);
                h[q] = hh; l[q] = ll;
            }
            *(s16x8*)&Ah[akg][ar + p * 64][0] = h;
            *(s16x8*)&Al[akg][ar + p * 64][0] = l;
            *(s16x8*)&Bh[bkg0 + p * 2][bc][0] = pbh[p];
            *(s16x8*)&Bl[bkg0 + p * 2][bc][0] = pbl[p];
        }
    };

    loadA(0); loadB(0);
    const int nk = K >> 5;
    for (int t = 0; t < nk; t++) {
        __syncthreads();               // WAR: previous tile's frag reads done
        storeLDS();
        __syncthreads();               // RAW: tile visible
        if (t + 1 < nk) { loadA((t + 1) << 5); loadB((t + 1) << 5); }  // overlap

        s16x8 a_hi[4], b_hi[4], tmp[4];
        #pragma unroll
        for (int x = 0; x < 4; x++) a_hi[x] = *pAh[x];
        #pragma unroll
        for (int x = 0; x < 4; x++) b_hi[x] = *pBh[x];
        #pragma unroll
        for (int mt = 0; mt < 4; mt++)
            #pragma unroll
            for (int nt = 0; nt < 4; nt++)
                acc[mt][nt] = __builtin_amdgcn_mfma_f32_16x16x32_bf16(
                    a_hi[mt], b_hi[nt], acc[mt][nt], 0, 0, 0);
        #pragma unroll
        for (int x = 0; x < 4; x++) tmp[x] = *pBl[x];
        #pragma unroll
        for (int mt = 0; mt < 4; mt++)
            #pragma unroll
            for (int nt = 0; nt < 4; nt++)
                acc[mt][nt] = __builtin_amdgcn_mfma_f32_16x16x32_bf16(
                    a_hi[mt], tmp[nt], acc[mt][nt], 0, 0, 0);
        #pragma unroll
        for (int x = 0; x < 4; x++) tmp[x] = *pAl[x];
        #pragma unroll
        for (int mt = 0; mt < 4; mt++)
            #pragma unroll
            for (int nt = 0; nt < 4; nt++)
                acc[mt][nt] = __builtin_amdgcn_mfma_f32_16x16x32_bf16(
                    tmp[mt], b_hi[nt], acc[mt][nt], 0, 0, 0);
    }

    // epilogue: C/D layout = col (lane&15), row (lane>>4)*4 + reg
    #pragma unroll
    for (int mt = 0; mt < 4; mt++) {
        #pragma unroll
        for (int q = 0; q < 4; q++) {
            int m = m0 + wm + mt * 16 + kg * 4 + q;
            #pragma unroll
            for (int nt = 0; nt < 4; nt++) {
                int n = n0 + wn + nt * 16 + rsel;
                if (n < N) {
                    float v = acc[mt][nt][q];
                    if (BIAS)  v += bias[n];
                    if (RELU)  v = fmaxf(v, 0.f);
                    if (RESID) v += resid[(size_t)m * N + n];
                    C[(size_t)m * N + n] = v;
                }
            }
        }
    }
}

// ---------------------------------------------------------------------------
// Legacy f32 SGEMM — kept ONLY as a fallback for the vocab projection if the
// workspace is too small to host fc_w's transposed/split copy.
// ---------------------------------------------------------------------------
template<bool BIAS, bool RELU, bool RESID>
__global__ __launch_bounds__(256)
void gemm_k(const float* __restrict__ A, const float* __restrict__ Bw,
            const float* __restrict__ bias, const float* __restrict__ resid,
            float* __restrict__ C, int M, int N, int K)
{
    __shared__ float As[8][128];
    __shared__ float Bs[8][128];
    const int tid = threadIdx.x;
    const int tx = tid & 15, ty = tid >> 4;
    const int m0 = blockIdx.y * 128, n0 = blockIdx.x * 128;
    float acc[8][8] = {};
    const int arow = tid >> 1;
    const int akk  = (tid & 1) * 4;
    const int brow = tid >> 5;
    const int bcol = (tid & 31) * 4;
    const int am   = m0 + arow;

    for (int k0 = 0; k0 < K; k0 += 8) {
        float a4[4];
        if (am < M) {
            const float* ap = A + (size_t)am * K + k0 + akk;
            float4 t = *(const float4*)ap;
            a4[0] = t.x; a4[1] = t.y; a4[2] = t.z; a4[3] = t.w;
        } else { a4[0] = a4[1] = a4[2] = a4[3] = 0.f; }
        #pragma unroll
        for (int q = 0; q < 4; q++) As[akk + q][arow] = a4[q];
        {
            const int nb = n0 + bcol;
            const float* bp = Bw + (size_t)(k0 + brow) * N + nb;
            float b4[4];
            if (nb + 3 < N) {
                float2 u0 = *(const float2*)bp;
                float2 u1 = *(const float2*)(bp + 2);
                b4[0] = u0.x; b4[1] = u0.y; b4[2] = u1.x; b4[3] = u1.y;
            } else {
                #pragma unroll
                for (int q = 0; q < 4; q++) b4[q] = (nb + q < N) ? bp[q] : 0.f;
            }
            #pragma unroll
            for (int q = 0; q < 4; q++) Bs[brow][bcol + q] = b4[q];
        }
        __syncthreads();
        #pragma unroll
        for (int kk = 0; kk < 8; kk++) {
            float4 a0 = *(const float4*)&As[kk][ty * 8];
            float4 a1 = *(const float4*)&As[kk][ty * 8 + 4];
            float4 b0 = *(const float4*)&Bs[kk][tx * 8];
            float4 b1 = *(const float4*)&Bs[kk][tx * 8 + 4];
            float av[8] = {a0.x,a0.y,a0.z,a0.w,a1.x,a1.y,a1.z,a1.w};
            float bv[8] = {b0.x,b0.y,b0.z,b0.w,b1.x,b1.y,b1.z,b1.w};
            #pragma unroll
            for (int i = 0; i < 8; i++)
                #pragma unroll
                for (int j = 0; j < 8; j++)
                    acc[i][j] += av[i] * bv[j];
        }
        __syncthreads();
    }
    #pragma unroll
    for (int i = 0; i < 8; i++) {
        int m = m0 + ty * 8 + i;
        if (m >= M) continue;
        #pragma unroll
        for (int j = 0; j < 8; j++) {
            int n = n0 + tx * 8 + j;
            if (n >= N) continue;
            float v = acc[i][j];
            if (BIAS)  v += bias[n];
            if (RELU)  v = fmaxf(v, 0.f);
            if (RESID) v += resid[(size_t)m * N + n];
            C[(size_t)m * N + n] = v;
        }
    }
}

// ---------------------------------------------------------------------------
// Self-attention: one block per batch, all 8 heads. Lq=Lk=10, causal+len mask.
// ---------------------------------------------------------------------------
__global__ __launch_bounds__(256)
void self_attn_k(const float* __restrict__ Qb, const float* __restrict__ KVP,
                 const int* __restrict__ lengths, float* __restrict__ O, int b0)
{
    __shared__ float qs[L_ * D_];
    __shared__ float ks[L_ * D_];
    __shared__ float vs[L_ * D_];
    __shared__ float sc[H_ * L_ * L_];
    int bl  = blockIdx.x;
    int b   = b0 + bl;
    int tid = threadIdx.x;
    int len = lengths[b];

    for (int p = tid; p < L_ * D_; p += 256) {
        int row = p >> 9, col = p & 511;
        qs[p] = Qb[((size_t)(b * L_ + row)) * D_ + col];
        ks[p] = KVP[((size_t)(bl * L_ + row)) * 1024 + col];
        vs[p] = KVP[((size_t)(bl * L_ + row)) * 1024 + 512 + col];
    }
    __syncthreads();

    for (int p = tid; p < H_ * L_ * L_; p += 256) {
        int h = p / (L_ * L_), r = p % (L_ * L_), i = r / L_, j = r % L_;
        float s = -1e30f;
        if (j <= i && j < len) {
            const float* qq = &qs[i * D_ + h * 64];
            const float* kk = &ks[j * D_ + h * 64];
            float d = 0.f;
            #pragma unroll
            for (int d0 = 0; d0 < 64; d0++) d += qq[d0] * kk[d0];
            s = d * 0.125f;
        }
        sc[p] = s;
    }
    __syncthreads();

    if (tid < H_ * L_) {
        int base = tid * L_;
        float mx = -1e30f;
        for (int j = 0; j < L_; j++) mx = fmaxf(mx, sc[base + j]);
        float sum = 0.f;
        for (int j = 0; j < L_; j++) { float e = expf(sc[base + j] - mx); sc[base + j] = e; sum += e; }
        float inv = 1.f / sum;
        for (int j = 0; j < L_; j++) sc[base + j] *= inv;
    }
    __syncthreads();

    for (int p = tid; p < L_ * D_; p += 256) {
        int i = p >> 9, col = p & 511, h = col >> 6;
        float o = 0.f;
        #pragma unroll
        for (int j = 0; j < L_; j++) o += sc[(h * L_ + i) * L_ + j] * vs[j * D_ + col];
        O[((size_t)(b * L_ + i)) * D_ + col] = o;
    }
}

// ---------------------------------------------------------------------------
// Cross-attention: one block per (local batch, head). Lq=10, Lk=70, no mask.
// ---------------------------------------------------------------------------
__global__ __launch_bounds__(256)
void cross_attn_k(const float* __restrict__ Qb, const float* __restrict__ KVP,
                  float* __restrict__ O, int b0)
{
    __shared__ float qs[L_ * 64];
    __shared__ float ks[BOARD_ * 64];
    __shared__ float vs[BOARD_ * 64];
    __shared__ float sc[L_ * BOARD_];
    int blk = blockIdx.x;
    int bl  = blk >> 3;
    int h   = blk & 7;
    int b   = b0 + bl;
    int tid = threadIdx.x;

    for (int p = tid; p < L_ * 64; p += 256) {
        int i = p >> 6, d = p & 63;
        qs[p] = Qb[((size_t)(b * L_ + i)) * D_ + h * 64 + d];
    }
    for (int p = tid; p < BOARD_ * 64; p += 256) {
        int j = p >> 6, d = p & 63;
        size_t kr = (size_t)(bl * BOARD_ + j);
        ks[p] = KVP[kr * 1024 + h * 64 + d];
        vs[p] = KVP[kr * 1024 + 512 + h * 64 + d];
    }
    __syncthreads();

    for (int p = tid; p < L_ * BOARD_; p += 256) {
        int i = p / BOARD_, j = p % BOARD_;
        float d = 0.f;
        #pragma unroll
        for (int d0 = 0; d0 < 64; d0++) d += qs[i * 64 + d0] * ks[j * 64 + d0];
        sc[p] = d * 0.125f;
    }
    __syncthreads();

    if (tid < L_) {
        float mx = -1e30f;
        for (int j = 0; j < BOARD_; j++) mx = fmaxf(mx, sc[tid * BOARD_ + j]);
        float sum = 0.f;
        for (int j = 0; j < BOARD_; j++) {
            float e = expf(sc[tid * BOARD_ + j] - mx);
            sc[tid * BOARD_ + j] = e; sum += e;
        }
        float inv = 1.f / sum;
        for (int j = 0; j < BOARD_; j++) sc[tid * BOARD_ + j] *= inv;
    }
    __syncthreads();

    for (int p = tid; p < L_ * 64; p += 256) {
        int i = p >> 6, d = p & 63;
        float o = 0.f;
        for (int j = 0; j < BOARD_; j++) o += sc[i * BOARD_ + j] * vs[j * 64 + d];
        O[((size_t)(b * L_ + i)) * D_ + h * 64 + d] = o;
    }
}

// ---------------------------------------------------------------------------
// Host-side orchestration.
// d_out (40.43M f32 = 161.7 MB): X @0 | Q @10.49M | U @20.97M (<=18.35M elems)
//   | WT tail @39.32M elems (2 x 1,048,576 bf16 = 4 MB, fits in 4.42 MB slack)
// d_ws: XN (41.9 MB) [+ fc_wT hi/lo 4 MB if ws_size permits].
// FFN's w1T pair lives in the Q region (dead during FFN).
// ---------------------------------------------------------------------------
extern "C" void kernel_launch(void* const* d_in, const int* in_sizes, int n_in,
                              void* d_out, int out_size, void* d_ws, size_t ws_size,
                              hipStream_t stream)
{
    (void)in_sizes; (void)n_in; (void)out_size;
    const int*   moves   = (const int*)d_in[0];
    const int*   lengths = (const int*)d_in[1];
    const float* boards  = (const float*)d_in[2];
    const float* emb     = (const float*)d_in[3];
    const float* pos     = (const float*)d_in[4];
    const float* sa_ln_g = (const float*)d_in[5];
    const float* sa_ln_b = (const float*)d_in[6];
    const float* sa_wq   = (const float*)d_in[7];
    const float* sa_bq   = (const float*)d_in[8];
    const float* sa_wkv  = (const float*)d_in[9];
    const float* sa_bkv  = (const float*)d_in[10];
    const float* sa_wo   = (const float*)d_in[11];
    const float* sa_bo   = (const float*)d_in[12];
    const float* ca_ln_g = (const float*)d_in[13];
    const float* ca_ln_b = (const float*)d_in[14];
    const float* ca_wq   = (const float*)d_in[15];
    const float* ca_bq   = (const float*)d_in[16];
    const float* ca_wkv  = (const float*)d_in[17];
    const float* ca_bkv  = (const float*)d_in[18];
    const float* ca_wo   = (const float*)d_in[19];
    const float* ca_bo   = (const float*)d_in[20];
    const float* ff_ln_g = (const float*)d_in[21];
    const float* ff_ln_b = (const float*)d_in[22];
    const float* ff_w1   = (const float*)d_in[23];
    const float* ff_b1   = (const float*)d_in[24];
    const float* ff_w2   = (const float*)d_in[25];
    const float* ff_b2   = (const float*)d_in[26];
    const float* fin_g   = (const float*)d_in[27];
    const float* fin_b   = (const float*)d_in[28];
    const float* fc_w    = (const float*)d_in[29];
    const float* fc_b    = (const float*)d_in[30];

    float* X  = (float*)d_out;                    // 10,485,760 elems
    float* Q  = X + (size_t)ROWS_ * D_;           // 10,485,760 elems
    float* U  = Q + (size_t)ROWS_ * D_;           // <= 18,350,080 elems
    const size_t WSLAB = (size_t)2048 * 512;      // 1,048,576 shorts / array
    short* WThi = (short*)(U + (size_t)17920 * 1024);   // d_out tail, 4 MB
    short* WTlo = WThi + WSLAB;
    short* QThi = (short*)Q;                      // Q region (dead during FFN)
    short* QTlo = QThi + WSLAB;
    float* XN = (float*)d_ws;                     // 10,485,760 elems
    short* FThi = (short*)(XN + (size_t)ROWS_ * D_);    // fc_wT, if ws allows
    short* FTlo = FThi + WSLAB;
    const bool ws_wt = ws_size >= (size_t)ROWS_ * D_ * 4 + 2 * WSLAB * sizeof(short);

    const int lnGrid = ROWS_ / 4;
    #define TGRID(N, K) dim3(((N) + 31) / 32, (K) / 32)

    embed_k<<<(ROWS_ * D_ + 255) / 256, 256, 0, stream>>>(moves, emb, pos, X);

    for (int i = 0; i < NL_; i++) {
        // ---------------- self-attention ----------------
        ln_k<<<lnGrid, 256, 0, stream>>>(X, sa_ln_g + i * D_, sa_ln_b + i * D_, XN, ROWS_);
        tsplit_k<<<TGRID(512, 512), 256, 0, stream>>>(sa_wq + (size_t)i * D_ * 512, WThi, WTlo, 512, 512);
        mgemm_k<true, false, false><<<dim3(4, 160), 256, 0, stream>>>(
            XN, WThi, WTlo, sa_bq + i * 512, nullptr, Q, ROWS_, 512, 512);
        tsplit_k<<<TGRID(1024, 512), 256, 0, stream>>>(sa_wkv + (size_t)i * D_ * 1024, WThi, WTlo, 512, 1024);
        for (int c = 0; c < 2; c++) {                 // 1024 batches / chunk
            const int RB = 1024, RR = RB * L_;        // 10240 rows
            mgemm_k<true, false, false><<<dim3(8, RR / 128), 256, 0, stream>>>(
                XN + (size_t)c * RR * D_, WThi, WTlo, sa_bkv + i * 1024, nullptr,
                U, RR, 1024, 512);
            self_attn_k<<<RB, 256, 0, stream>>>(Q, U, lengths, XN, c * RB);
        }
        tsplit_k<<<TGRID(512, 512), 256, 0, stream>>>(sa_wo + (size_t)i * 512 * D_, WThi, WTlo, 512, 512);
        mgemm_k<true, false, true><<<dim3(4, 160), 256, 0, stream>>>(
            XN, WThi, WTlo, sa_bo + i * D_, X, X, ROWS_, 512, 512);

        // ---------------- cross-attention ----------------
        ln_k<<<lnGrid, 256, 0, stream>>>(X, ca_ln_g + i * D_, ca_ln_b + i * D_, XN, ROWS_);
        tsplit_k<<<TGRID(512, 512), 256, 0, stream>>>(ca_wq + (size_t)i * D_ * 512, WThi, WTlo, 512, 512);
        mgemm_k<true, false, false><<<dim3(4, 160), 256, 0, stream>>>(
            XN, WThi, WTlo, ca_bq + i * 512, nullptr, Q, ROWS_, 512, 512);
        tsplit_k<<<TGRID(1024, 512), 256, 0, stream>>>(ca_wkv + (size_t)i * D_ * 1024, WThi, WTlo, 512, 1024);
        for (int c = 0; c < B_ / 256; c++) {          // 256 batches / chunk
            const int CHB = 256, KR = CHB * BOARD_;   // 17920 rows
            mgemm_k<true, false, false><<<dim3(8, KR / 128), 256, 0, stream>>>(
                boards + (size_t)c * KR * D_, WThi, WTlo, ca_bkv + i * 1024, nullptr,
                U, KR, 1024, 512);
            cross_attn_k<<<CHB * H_, 256, 0, stream>>>(Q, U, XN, c * CHB);
        }
        tsplit_k<<<TGRID(512, 512), 256, 0, stream>>>(ca_wo + (size_t)i * 512 * D_, WThi, WTlo, 512, 512);
        mgemm_k<true, false, true><<<dim3(4, 160), 256, 0, stream>>>(
            XN, WThi, WTlo, ca_bo + i * D_, X, X, ROWS_, 512, 512);

        // ---------------- FFN ----------------
        ln_k<<<lnGrid, 256, 0, stream>>>(X, ff_ln_g + i * D_, ff_ln_b + i * D_, XN, ROWS_);
        tsplit_k<<<TGRID(2048, 512), 256, 0, stream>>>(ff_w1 + (size_t)i * D_ * DI_, QThi, QTlo, 512, 2048);
        tsplit_k<<<TGRID(512, 2048), 256, 0, stream>>>(ff_w2 + (size_t)i * DI_ * D_, WThi, WTlo, 2048, 512);
        for (int rc = 0; rc < 4; rc++) {
            const int RC = ROWS_ / 4;                 // 5120 rows
            mgemm_k<true, true, false><<<dim3(16, RC / 128), 256, 0, stream>>>(
                XN + (size_t)rc * RC * D_, QThi, QTlo, ff_b1 + i * DI_, nullptr,
                U, RC, DI_, 512);
            mgemm_k<true, false, true><<<dim3(4, RC / 128), 256, 0, stream>>>(
                U, WThi, WTlo, ff_b2 + i * D_,
                X + (size_t)rc * RC * D_, X + (size_t)rc * RC * D_, RC, 512, DI_);
        }
    }

    // ---------------- final LN + vocab projection ----------------
    ln_k<<<lnGrid, 256, 0, stream>>>(X, fin_g, fin_b, XN, ROWS_);
    if (ws_wt) {
        tsplit_k<<<TGRID(V_, 512), 256, 0, stream>>>(fc_w, FThi, FTlo, 512, V_);
        mgemm_k<true, false, false><<<dim3((V_ + 127) / 128, 160), 256, 0, stream>>>(
            XN, FThi, FTlo, fc_b, nullptr, (float*)d_out, ROWS_, V_, 512);
    } else {
        gemm_k<true, false, false><<<dim3((V_ + 127) / 128, 160), 256, 0, stream>>>(
            XN, fc_w, fc_b, nullptr, (float*)d_out, ROWS_, V_, 512);
    }
}

// Round 3
// 14437.152 us; speedup vs baseline: 2.5198x; 1.0796x over previous
//
#include <hip/hip_runtime.h>
#include <math.h>

#define B_     2048
#define L_     10
#define D_     512
#define H_     8
#define V_     1974
#define DI_    2048
#define NL_    6
#define BOARD_ 70
#define ROWS_  (B_ * L_)            /* 20480 */
#define SQRT_D 22.627416997969522f

typedef __attribute__((ext_vector_type(8)))  short s16x8;   // 8 bf16 (4 VGPR)
typedef __attribute__((ext_vector_type(4)))  float f32x4;
typedef __attribute__((ext_vector_type(16))) float f32x16;

// Dekker-style split: x ~= hi + lo, both bf16 (truncated). Residual ~2^-16|x|.
__device__ __forceinline__ void split2(float x, short &hi, short &lo)
{
    unsigned u = __float_as_uint(x);
    hi = (short)(u >> 16);
    float hf = __uint_as_float(u & 0xffff0000u);
    lo = (short)(__float_as_uint(x - hf) >> 16);
}

// async global->LDS, 16 B per lane. LDS dest = wave-uniform base + lane*16.
__device__ __forceinline__ void gload_lds16(const void* g, void* l)
{
    __builtin_amdgcn_global_load_lds(
        (const __attribute__((address_space(1))) unsigned int*)g,
        (__attribute__((address_space(3))) unsigned int*)l, 16, 0, 0);
}

// bank-group XOR offsets for A staging: g(kg) = {0,4,2,6}
__device__ __forceinline__ int gofs(int kg) { return ((kg & 1) << 2) | (kg & 2); }

// ---------------------------------------------------------------------------
// Embedding: X[b,l,:] = emb[moves[b,l],:]*sqrt(D) + pos[l,:]
// ---------------------------------------------------------------------------
__global__ __launch_bounds__(256)
void embed_k(const int* __restrict__ moves, const float* __restrict__ emb,
             const float* __restrict__ pos, float* __restrict__ X)
{
    int idx = blockIdx.x * 256 + threadIdx.x;
    if (idx >= ROWS_ * D_) return;
    int d  = idx & 511;
    int bl = idx >> 9;
    int l  = bl % L_;
    int mv = moves[bl];
    X[idx] = emb[mv * D_ + d] * SQRT_D + pos[l * D_ + d];
}

// ---------------------------------------------------------------------------
// LayerNorm over D=512 (f32). One wave per row, 4 rows/block.
// ---------------------------------------------------------------------------
__global__ __launch_bounds__(256)
void ln_k(const float* __restrict__ X, const float* __restrict__ g,
          const float* __restrict__ bta, float* __restrict__ Y, int rows)
{
    int wave = threadIdx.x >> 6;
    int lane = threadIdx.x & 63;
    int row  = blockIdx.x * 4 + wave;
    if (row >= rows) return;
    const float* x = X + (size_t)row * D_;
    float4 t0 = *(const float4*)&x[lane * 8];
    float4 t1 = *(const float4*)&x[lane * 8 + 4];
    float v[8] = { t0.x, t0.y, t0.z, t0.w, t1.x, t1.y, t1.z, t1.w };
    float s1 = 0.f, s2 = 0.f;
    #pragma unroll
    for (int q = 0; q < 8; q++) { s1 += v[q]; s2 += v[q] * v[q]; }
    #pragma unroll
    for (int off = 32; off; off >>= 1) {
        s1 += __shfl_xor(s1, off);
        s2 += __shfl_xor(s2, off);
    }
    float m   = s1 * (1.f / D_);
    float var = s2 * (1.f / D_) - m * m;
    float r   = 1.0f / sqrtf(var + 1e-5f);
    float* y = Y + (size_t)row * D_;
    #pragma unroll
    for (int q = 0; q < 8; q++) {
        int d = lane * 8 + q;
        y[d] = (v[q] - m) * r * g[d] + bta[d];
    }
}

// ---------------------------------------------------------------------------
// Transpose + bf16 hi/lo split:  W (KxN f32, row-major) -> Thi/Tlo (NxK bf16)
// 32x32 tiles. Rows nn >= N are zero-filled (launch grid may pad N up).
// ---------------------------------------------------------------------------
__global__ __launch_bounds__(256)
void tsplit_k(const float* __restrict__ W, short* __restrict__ Thi,
              short* __restrict__ Tlo, int K, int N)
{
    __shared__ float t[32][33];
    int n0 = blockIdx.x * 32, k0 = blockIdx.y * 32;
    int c = threadIdx.x & 31, r = threadIdx.x >> 5;      // r: 0..7
    #pragma unroll
    for (int i = 0; i < 4; i++) {
        int kk = k0 + r + i * 8, nn = n0 + c;
        t[r + i * 8][c] = (nn < N) ? W[(size_t)kk * N + nn] : 0.f;
    }
    __syncthreads();
    #pragma unroll
    for (int i = 0; i < 4; i++) {
        int nn = n0 + r + i * 8;     // output row (n)
        int kk = k0 + c;             // output col (k)
        short hi, lo; split2(t[c][r + i * 8], hi, lo);
        Thi[(size_t)nn * K + kk] = hi;
        Tlo[(size_t)nn * K + kk] = lo;
    }
}

// ---------------------------------------------------------------------------
// MFMA GEMM v2, split-bf16 emulation of f32 (3 passes: hh + h*lo + lo*h).
// Block 128 x BN, 256 threads = 4 waves (2x2), wave tile 64 x (BN/2),
// v_mfma_f32_32x32x16_bf16 fragments (2 m-frags x NF n-frags, NF = BN/64).
// A (f32) reg-staged + split on the fly, LDS XOR-swizzled rows (write-
// conflict-free, read-conflict-free). B (pre-split NxK bf16) staged via
// global_load_lds into a double buffer -> no B register staging, no B
// ds_writes. Grid: x = M/128 (consecutive blocks share the B panel -> L2).
// Requires M % 128 == 0, K % 32 == 0. N guarded in epilogue only (B slabs
// are allocated/zero-filled to a multiple of 256 cols).
// ---------------------------------------------------------------------------
template<int BN, bool BIAS, bool RELU, bool RESID>
__global__ __launch_bounds__(256, 2)
void mg2_k(const float* __restrict__ A,
           const short* __restrict__ BThi, const short* __restrict__ BTlo,
           const float* __restrict__ bias, const float* __restrict__ resid,
           float* __restrict__ C, int M, int N, int K)
{
    constexpr int NF = BN / 64;                  // n-frags per wave (and 64-col chunks)
    __shared__ short Ah[4][128][8], Al[4][128][8];
    __shared__ short Bh[2][4][BN][8], Bl[2][4][BN][8];

    const int tid  = threadIdx.x;
    const int lane = tid & 63;
    const int wv   = tid >> 6;
    const int m0 = blockIdx.x * 128, n0 = blockIdx.y * BN;

    // A staging assignment: rows {ar, ar+64}, k-group akg (8 k each)
    const int ar  = tid >> 2;
    const int akg = tid & 3;

    // wave/frag geometry
    const int wm  = (wv >> 1) * 64, wn = (wv & 1) * (BN / 2);
    const int l31 = lane & 31, lhi = lane >> 5;

    f32x16 acc[2][NF];
    #pragma unroll
    for (int mf = 0; mf < 2; mf++)
        #pragma unroll
        for (int nf = 0; nf < NF; nf++)
            #pragma unroll
            for (int r = 0; r < 16; r++) acc[mf][nf][r] = 0.f;

    f32x4 pa[2][2];
    auto loadA = [&](int k0) {
        #pragma unroll
        for (int p = 0; p < 2; p++) {
            const float* ap = A + (size_t)(m0 + ar + p * 64) * K + k0 + akg * 8;
            pa[p][0] = *(const f32x4*)ap;
            pa[p][1] = *(const f32x4*)(ap + 4);
        }
    };
    auto storeA = [&]() {
        const int g = gofs(akg);
        #pragma unroll
        for (int p = 0; p < 2; p++) {
            s16x8 h, l;
            #pragma unroll
            for (int q = 0; q < 8; q++) {
                float x = (q < 4) ? pa[p][0][q] : pa[p][1][q - 4];
                short hh, ll; split2(x, hh, ll);
                h[q] = hh; l[q] = ll;
            }
            const int row = (ar + p * 64) ^ g;
            *(s16x8*)&Ah[akg][row][0] = h;
            *(s16x8*)&Al[akg][row][0] = l;
        }
    };
    auto issueB = [&](int k0, int bb) {
        #pragma unroll
        for (int cb = 0; cb < NF; cb++) {
            const size_t go = (size_t)(n0 + cb * 64 + lane) * K + k0 + wv * 8;
            gload_lds16(BThi + go, &Bh[bb][wv][cb * 64][0]);
            gload_lds16(BTlo + go, &Bl[bb][wv][cb * 64][0]);
        }
    };
    auto compute = [&](int bb) {
        #pragma unroll
        for (int ks = 0; ks < 2; ks++) {
            const int kg = 2 * ks + lhi;
            const int g  = gofs(kg);
            s16x8 ah[2], bh[NF], bl[NF], al[2];
            #pragma unroll
            for (int mf = 0; mf < 2; mf++)
                ah[mf] = *(const s16x8*)&Ah[kg][(wm + mf * 32 + l31) ^ g][0];
            #pragma unroll
            for (int nf = 0; nf < NF; nf++)
                bh[nf] = *(const s16x8*)&Bh[bb][kg][wn + nf * 32 + l31][0];
            #pragma unroll
            for (int mf = 0; mf < 2; mf++)
                #pragma unroll
                for (int nf = 0; nf < NF; nf++)
                    acc[mf][nf] = __builtin_amdgcn_mfma_f32_32x32x16_bf16(
                        ah[mf], bh[nf], acc[mf][nf], 0, 0, 0);
            #pragma unroll
            for (int nf = 0; nf < NF; nf++)
                bl[nf] = *(const s16x8*)&Bl[bb][kg][wn + nf * 32 + l31][0];
            #pragma unroll
            for (int mf = 0; mf < 2; mf++)
                #pragma unroll
                for (int nf = 0; nf < NF; nf++)
                    acc[mf][nf] = __builtin_amdgcn_mfma_f32_32x32x16_bf16(
                        ah[mf], bl[nf], acc[mf][nf], 0, 0, 0);
            #pragma unroll
            for (int mf = 0; mf < 2; mf++)
                al[mf] = *(const s16x8*)&Al[kg][(wm + mf * 32 + l31) ^ g][0];
            #pragma unroll
            for (int mf = 0; mf < 2; mf++)
                #pragma unroll
                for (int nf = 0; nf < NF; nf++)
                    acc[mf][nf] = __builtin_amdgcn_mfma_f32_32x32x16_bf16(
                        al[mf], bh[nf], acc[mf][nf], 0, 0, 0);
        }
    };

    issueB(0, 0);
    loadA(0);
    __syncthreads();                 // drain: B(0) in LDS, A(0) in regs
    const int nk = K >> 5;
    for (int t = 0; t < nk; t++) {
        storeA();                    // A(t) regs -> LDS
        __syncthreads();             // A(t) visible
        if (t + 1 < nk) {            // next tile in flight during compute
            issueB((t + 1) << 5, (t + 1) & 1);
            loadA((t + 1) << 5);
        }
        compute(t & 1);
        __syncthreads();             // WAR on A-LDS + drains next-tile loads
    }

    // epilogue: C/D 32x32 layout: col = lane&31, row = (r&3) + 8*(r>>2) + 4*(lane>>5)
    #pragma unroll
    for (int mf = 0; mf < 2; mf++) {
        #pragma unroll
        for (int nf = 0; nf < NF; nf++) {
            const int n = n0 + wn + nf * 32 + l31;
            if (n < N) {
                const float bv = BIAS ? bias[n] : 0.f;
                #pragma unroll
                for (int r = 0; r < 16; r++) {
                    const int m = m0 + wm + mf * 32 + (r & 3) + 8 * (r >> 2) + 4 * lhi;
                    float v = acc[mf][nf][r] + bv;
                    if (RELU)  v = fmaxf(v, 0.f);
                    if (RESID) v += resid[(size_t)m * N + n];
                    C[(size_t)m * N + n] = v;
                }
            }
        }
    }
}

// ---------------------------------------------------------------------------
// Legacy f32 SGEMM — fallback for the vocab projection if the workspace is
// too small to host fc_w's transposed/split copy.
// ---------------------------------------------------------------------------
template<bool BIAS, bool RELU, bool RESID>
__global__ __launch_bounds__(256)
void gemm_k(const float* __restrict__ A, const float* __restrict__ Bw,
            const float* __restrict__ bias, const float* __restrict__ resid,
            float* __restrict__ C, int M, int N, int K)
{
    __shared__ float As[8][128];
    __shared__ float Bs[8][128];
    const int tid = threadIdx.x;
    const int tx = tid & 15, ty = tid >> 4;
    const int m0 = blockIdx.y * 128, n0 = blockIdx.x * 128;
    float acc[8][8] = {};
    const int arow = tid >> 1;
    const int akk  = (tid & 1) * 4;
    const int brow = tid >> 5;
    const int bcol = (tid & 31) * 4;
    const int am   = m0 + arow;

    for (int k0 = 0; k0 < K; k0 += 8) {
        float a4[4];
        if (am < M) {
            const float* ap = A + (size_t)am * K + k0 + akk;
            float4 t = *(const float4*)ap;
            a4[0] = t.x; a4[1] = t.y; a4[2] = t.z; a4[3] = t.w;
        } else { a4[0] = a4[1] = a4[2] = a4[3] = 0.f; }
        #pragma unroll
        for (int q = 0; q < 4; q++) As[akk + q][arow] = a4[q];
        {
            const int nb = n0 + bcol;
            const float* bp = Bw + (size_t)(k0 + brow) * N + nb;
            float b4[4];
            if (nb + 3 < N) {
                float2 u0 = *(const float2*)bp;
                float2 u1 = *(const float2*)(bp + 2);
                b4[0] = u0.x; b4[1] = u0.y; b4[2] = u1.x; b4[3] = u1.y;
            } else {
                #pragma unroll
                for (int q = 0; q < 4; q++) b4[q] = (nb + q < N) ? bp[q] : 0.f;
            }
            #pragma unroll
            for (int q = 0; q < 4; q++) Bs[brow][bcol + q] = b4[q];
        }
        __syncthreads();
        #pragma unroll
        for (int kk = 0; kk < 8; kk++) {
            float4 a0 = *(const float4*)&As[kk][ty * 8];
            float4 a1 = *(const float4*)&As[kk][ty * 8 + 4];
            float4 b0 = *(const float4*)&Bs[kk][tx * 8];
            float4 b1 = *(const float4*)&Bs[kk][tx * 8 + 4];
            float av[8] = {a0.x,a0.y,a0.z,a0.w,a1.x,a1.y,a1.z,a1.w};
            float bv[8] = {b0.x,b0.y,b0.z,b0.w,b1.x,b1.y,b1.z,b1.w};
            #pragma unroll
            for (int i = 0; i < 8; i++)
                #pragma unroll
                for (int j = 0; j < 8; j++)
                    acc[i][j] += av[i] * bv[j];
        }
        __syncthreads();
    }
    #pragma unroll
    for (int i = 0; i < 8; i++) {
        int m = m0 + ty * 8 + i;
        if (m >= M) continue;
        #pragma unroll
        for (int j = 0; j < 8; j++) {
            int n = n0 + tx * 8 + j;
            if (n >= N) continue;
            float v = acc[i][j];
            if (BIAS)  v += bias[n];
            if (RELU)  v = fmaxf(v, 0.f);
            if (RESID) v += resid[(size_t)m * N + n];
            C[(size_t)m * N + n] = v;
        }
    }
}

// ---------------------------------------------------------------------------
// Self-attention: one block per batch, all 8 heads. Lq=Lk=10, causal+len mask.
// ---------------------------------------------------------------------------
__global__ __launch_bounds__(256)
void self_attn_k(const float* __restrict__ Qb, const float* __restrict__ KVP,
                 const int* __restrict__ lengths, float* __restrict__ O, int b0)
{
    __shared__ float qs[L_ * D_];
    __shared__ float ks[L_ * D_];
    __shared__ float vs[L_ * D_];
    __shared__ float sc[H_ * L_ * L_];
    int bl  = blockIdx.x;
    int b   = b0 + bl;
    int tid = threadIdx.x;
    int len = lengths[b];

    for (int p = tid; p < L_ * D_; p += 256) {
        int row = p >> 9, col = p & 511;
        qs[p] = Qb[((size_t)(b * L_ + row)) * D_ + col];
        ks[p] = KVP[((size_t)(bl * L_ + row)) * 1024 + col];
        vs[p] = KVP[((size_t)(bl * L_ + row)) * 1024 + 512 + col];
    }
    __syncthreads();

    for (int p = tid; p < H_ * L_ * L_; p += 256) {
        int h = p / (L_ * L_), r = p % (L_ * L_), i = r / L_, j = r % L_;
        float s = -1e30f;
        if (j <= i && j < len) {
            const float* qq = &qs[i * D_ + h * 64];
            const float* kk = &ks[j * D_ + h * 64];
            float d = 0.f;
            #pragma unroll
            for (int d0 = 0; d0 < 64; d0++) d += qq[d0] * kk[d0];
            s = d * 0.125f;
        }
        sc[p] = s;
    }
    __syncthreads();

    if (tid < H_ * L_) {
        int base = tid * L_;
        float mx = -1e30f;
        for (int j = 0; j < L_; j++) mx = fmaxf(mx, sc[base + j]);
        float sum = 0.f;
        for (int j = 0; j < L_; j++) { float e = expf(sc[base + j] - mx); sc[base + j] = e; sum += e; }
        float inv = 1.f / sum;
        for (int j = 0; j < L_; j++) sc[base + j] *= inv;
    }
    __syncthreads();

    for (int p = tid; p < L_ * D_; p += 256) {
        int i = p >> 9, col = p & 511, h = col >> 6;
        float o = 0.f;
        #pragma unroll
        for (int j = 0; j < L_; j++) o += sc[(h * L_ + i) * L_ + j] * vs[j * D_ + col];
        O[((size_t)(b * L_ + i)) * D_ + col] = o;
    }
}

// ---------------------------------------------------------------------------
// Cross-attention: one block per (local batch, head). Lq=10, Lk=70, no mask.
// ---------------------------------------------------------------------------
__global__ __launch_bounds__(256)
void cross_attn_k(const float* __restrict__ Qb, const float* __restrict__ KVP,
                  float* __restrict__ O, int b0)
{
    __shared__ float qs[L_ * 64];
    __shared__ float ks[BOARD_ * 64];
    __shared__ float vs[BOARD_ * 64];
    __shared__ float sc[L_ * BOARD_];
    int blk = blockIdx.x;
    int bl  = blk >> 3;
    int h   = blk & 7;
    int b   = b0 + bl;
    int tid = threadIdx.x;

    for (int p = tid; p < L_ * 64; p += 256) {
        int i = p >> 6, d = p & 63;
        qs[p] = Qb[((size_t)(b * L_ + i)) * D_ + h * 64 + d];
    }
    for (int p = tid; p < BOARD_ * 64; p += 256) {
        int j = p >> 6, d = p & 63;
        size_t kr = (size_t)(bl * BOARD_ + j);
        ks[p] = KVP[kr * 1024 + h * 64 + d];
        vs[p] = KVP[kr * 1024 + 512 + h * 64 + d];
    }
    __syncthreads();

    for (int p = tid; p < L_ * BOARD_; p += 256) {
        int i = p / BOARD_, j = p % BOARD_;
        float d = 0.f;
        #pragma unroll
        for (int d0 = 0; d0 < 64; d0++) d += qs[i * 64 + d0] * ks[j * 64 + d0];
        sc[p] = d * 0.125f;
    }
    __syncthreads();

    if (tid < L_) {
        float mx = -1e30f;
        for (int j = 0; j < BOARD_; j++) mx = fmaxf(mx, sc[tid * BOARD_ + j]);
        float sum = 0.f;
        for (int j = 0; j < BOARD_; j++) {
            float e = expf(sc[tid * BOARD_ + j] - mx);
            sc[tid * BOARD_ + j] = e; sum += e;
        }
        float inv = 1.f / sum;
        for (int j = 0; j < BOARD_; j++) sc[tid * BOARD_ + j] *= inv;
    }
    __syncthreads();

    for (int p = tid; p < L_ * 64; p += 256) {
        int i = p >> 6, d = p & 63;
        float o = 0.f;
        for (int j = 0; j < BOARD_; j++) o += sc[i * BOARD_ + j] * vs[j * 64 + d];
        O[((size_t)(b * L_ + i)) * D_ + h * 64 + d] = o;
    }
}

// ---------------------------------------------------------------------------
// Host-side orchestration.
// d_out (40.43M f32): X @0 | Q @10.49M | U @20.97M (<=18.35M elems)
//   | WT tail @39.32M elems (2 x 1,048,576 bf16 = 4 MB)
// d_ws: XN (41.9 MB) [+ fc_wT hi/lo 4 MB if ws_size permits].
// FFN's w1T pair lives in the Q region (dead during FFN).
// ---------------------------------------------------------------------------
extern "C" void kernel_launch(void* const* d_in, const int* in_sizes, int n_in,
                              void* d_out, int out_size, void* d_ws, size_t ws_size,
                              hipStream_t stream)
{
    (void)in_sizes; (void)n_in; (void)out_size;
    const int*   moves   = (const int*)d_in[0];
    const int*   lengths = (const int*)d_in[1];
    const float* boards  = (const float*)d_in[2];
    const float* emb     = (const float*)d_in[3];
    const float* pos     = (const float*)d_in[4];
    const float* sa_ln_g = (const float*)d_in[5];
    const float* sa_ln_b = (const float*)d_in[6];
    const float* sa_wq   = (const float*)d_in[7];
    const float* sa_bq   = (const float*)d_in[8];
    const float* sa_wkv  = (const float*)d_in[9];
    const float* sa_bkv  = (const float*)d_in[10];
    const float* sa_wo   = (const float*)d_in[11];
    const float* sa_bo   = (const float*)d_in[12];
    const float* ca_ln_g = (const float*)d_in[13];
    const float* ca_ln_b = (const float*)d_in[14];
    const float* ca_wq   = (const float*)d_in[15];
    const float* ca_bq   = (const float*)d_in[16];
    const float* ca_wkv  = (const float*)d_in[17];
    const float* ca_bkv  = (const float*)d_in[18];
    const float* ca_wo   = (const float*)d_in[19];
    const float* ca_bo   = (const float*)d_in[20];
    const float* ff_ln_g = (const float*)d_in[21];
    const float* ff_ln_b = (const float*)d_in[22];
    const float* ff_w1   = (const float*)d_in[23];
    const float* ff_b1   = (const float*)d_in[24];
    const float* ff_w2   = (const float*)d_in[25];
    const float* ff_b2   = (const float*)d_in[26];
    const float* fin_g   = (const float*)d_in[27];
    const float* fin_b   = (const float*)d_in[28];
    const float* fc_w    = (const float*)d_in[29];
    const float* fc_b    = (const float*)d_in[30];

    float* X  = (float*)d_out;                    // 10,485,760 elems
    float* Q  = X + (size_t)ROWS_ * D_;           // 10,485,760 elems
    float* U  = Q + (size_t)ROWS_ * D_;           // <= 18,350,080 elems
    const size_t WSLAB = (size_t)2048 * 512;      // 1,048,576 shorts / array
    short* WThi = (short*)(U + (size_t)17920 * 1024);   // d_out tail, 4 MB
    short* WTlo = WThi + WSLAB;
    short* QThi = (short*)Q;                      // Q region (dead during FFN)
    short* QTlo = QThi + WSLAB;
    float* XN = (float*)d_ws;                     // 10,485,760 elems
    short* FThi = (short*)(XN + (size_t)ROWS_ * D_);    // fc_wT, if ws allows
    short* FTlo = FThi + WSLAB;
    const bool ws_wt = ws_size >= (size_t)ROWS_ * D_ * 4 + 2 * WSLAB * sizeof(short);

    const int lnGrid = ROWS_ / 4;
    #define TGRID(N, K) dim3(((N) + 31) / 32, (K) / 32)

    embed_k<<<(ROWS_ * D_ + 255) / 256, 256, 0, stream>>>(moves, emb, pos, X);

    for (int i = 0; i < NL_; i++) {
        // ---------------- self-attention ----------------
        ln_k<<<lnGrid, 256, 0, stream>>>(X, sa_ln_g + i * D_, sa_ln_b + i * D_, XN, ROWS_);
        tsplit_k<<<TGRID(512, 512), 256, 0, stream>>>(sa_wq + (size_t)i * D_ * 512, WThi, WTlo, 512, 512);
        mg2_k<128, true, false, false><<<dim3(160, 4), 256, 0, stream>>>(
            XN, WThi, WTlo, sa_bq + i * 512, nullptr, Q, ROWS_, 512, 512);
        tsplit_k<<<TGRID(1024, 512), 256, 0, stream>>>(sa_wkv + (size_t)i * D_ * 1024, WThi, WTlo, 512, 1024);
        for (int c = 0; c < 2; c++) {                 // 1024 batches / chunk
            const int RB = 1024, RR = RB * L_;        // 10240 rows
            mg2_k<256, true, false, false><<<dim3(RR / 128, 4), 256, 0, stream>>>(
                XN + (size_t)c * RR * D_, WThi, WTlo, sa_bkv + i * 1024, nullptr,
                U, RR, 1024, 512);
            self_attn_k<<<RB, 256, 0, stream>>>(Q, U, lengths, XN, c * RB);
        }
        tsplit_k<<<TGRID(512, 512), 256, 0, stream>>>(sa_wo + (size_t)i * 512 * D_, WThi, WTlo, 512, 512);
        mg2_k<128, true, false, true><<<dim3(160, 4), 256, 0, stream>>>(
            XN, WThi, WTlo, sa_bo + i * D_, X, X, ROWS_, 512, 512);

        // ---------------- cross-attention ----------------
        ln_k<<<lnGrid, 256, 0, stream>>>(X, ca_ln_g + i * D_, ca_ln_b + i * D_, XN, ROWS_);
        tsplit_k<<<TGRID(512, 512), 256, 0, stream>>>(ca_wq + (size_t)i * D_ * 512, WThi, WTlo, 512, 512);
        mg2_k<128, true, false, false><<<dim3(160, 4), 256, 0, stream>>>(
            XN, WThi, WTlo, ca_bq + i * 512, nullptr, Q, ROWS_, 512, 512);
        tsplit_k<<<TGRID(1024, 512), 256, 0, stream>>>(ca_wkv + (size_t)i * D_ * 1024, WThi, WTlo, 512, 1024);
        for (int c = 0; c < B_ / 256; c++) {          // 256 batches / chunk
            const int CHB = 256, KR = CHB * BOARD_;   // 17920 rows
            mg2_k<256, true, false, false><<<dim3(KR / 128, 4), 256, 0, stream>>>(
                boards + (size_t)c * KR * D_, WThi, WTlo, ca_bkv + i * 1024, nullptr,
                U, KR, 1024, 512);
            cross_attn_k<<<CHB * H_, 256, 0, stream>>>(Q, U, XN, c * CHB);
        }
        tsplit_k<<<TGRID(512, 512), 256, 0, stream>>>(ca_wo + (size_t)i * 512 * D_, WThi, WTlo, 512, 512);
        mg2_k<128, true, false, true><<<dim3(160, 4), 256, 0, stream>>>(
            XN, WThi, WTlo, ca_bo + i * D_, X, X, ROWS_, 512, 512);

        // ---------------- FFN ----------------
        ln_k<<<lnGrid, 256, 0, stream>>>(X, ff_ln_g + i * D_, ff_ln_b + i * D_, XN, ROWS_);
        tsplit_k<<<TGRID(2048, 512), 256, 0, stream>>>(ff_w1 + (size_t)i * D_ * DI_, QThi, QTlo, 512, 2048);
        tsplit_k<<<TGRID(512, 2048), 256, 0, stream>>>(ff_w2 + (size_t)i * DI_ * D_, WThi, WTlo, 2048, 512);
        for (int rc = 0; rc < 4; rc++) {
            const int RC = ROWS_ / 4;                 // 5120 rows
            mg2_k<256, true, true, false><<<dim3(RC / 128, 8), 256, 0, stream>>>(
                XN + (size_t)rc * RC * D_, QThi, QTlo, ff_b1 + i * DI_, nullptr,
                U, RC, DI_, 512);
            mg2_k<128, true, false, true><<<dim3(RC / 128, 4), 256, 0, stream>>>(
                U, WThi, WTlo, ff_b2 + i * D_,
                X + (size_t)rc * RC * D_, X + (size_t)rc * RC * D_, RC, 512, DI_);
        }
    }

    // ---------------- final LN + vocab projection ----------------
    ln_k<<<lnGrid, 256, 0, stream>>>(X, fin_g, fin_b, XN, ROWS_);
    if (ws_wt) {
        // pad transpose grid to 2048 rows: rows >= V_ are zero-filled
        tsplit_k<<<dim3(2048 / 32, 512 / 32), 256, 0, stream>>>(fc_w, FThi, FTlo, 512, V_);
        mg2_k<256, true, false, false><<<dim3(160, 8), 256, 0, stream>>>(
            XN, FThi, FTlo, fc_b, nullptr, (float*)d_out, ROWS_, V_, 512);
    } else {
        gemm_k<true, false, false><<<dim3((V_ + 127) / 128, 160), 256, 0, stream>>>(
            XN, fc_w, fc_b, nullptr, (float*)d_out, ROWS_, V_, 512);
    }
}